// Round 5
// baseline (8067.184 us; speedup 1.0000x reference)
//
#include <hip/hip_runtime.h>

typedef __bf16 bf16;
typedef __bf16 bf16x4 __attribute__((ext_vector_type(4)));
typedef __bf16 bf16x8 __attribute__((ext_vector_type(8)));
typedef float f32x4 __attribute__((ext_vector_type(4)));
typedef unsigned long long u64;
typedef unsigned int u32;

#define T_STEPS 1024
#define BATCH   64
#define DIN     256
#define HID     1024
#define NBLK    128   // 64 feature-groups x 2 batch-halves
#define RING    8     // h ring-buffer depth (slot = t & 7)

// ---------------------------------------------------------------------------
// Kernel 1: xproj[t][b][h] = sum_d x[b][t][d] * w_ih[h][d]   (bf16 out)
// ---------------------------------------------------------------------------
__global__ __launch_bounds__(256) void xproj_gemm(
    const float* __restrict__ x, const float* __restrict__ w_ih,
    bf16* __restrict__ xproj)
{
    __shared__ bf16 As[128 * 40];
    __shared__ bf16 Bs[128 * 40];
    const int tid = threadIdx.x;
    const int m0 = blockIdx.x * 128;
    const int n0 = blockIdx.y * 128;
    const int w = tid >> 6, lane = tid & 63;
    const int r = lane & 15, q = lane >> 4;

    f32x4 acc[2][8];
    #pragma unroll
    for (int i = 0; i < 2; i++)
        #pragma unroll
        for (int j = 0; j < 8; j++)
            acc[i][j] = (f32x4){0.f, 0.f, 0.f, 0.f};

    for (int kk = 0; kk < 8; kk++) {
        const int k0 = kk * 32;
        __syncthreads();
        #pragma unroll
        for (int j = 0; j < 4; j++) {
            int u = tid + j * 256;
            int row = u >> 3, c4 = u & 7;
            float4 fa = *(const float4*)&x[(size_t)(m0 + row) * DIN + k0 + c4 * 4];
            bf16x4 va = { (bf16)fa.x, (bf16)fa.y, (bf16)fa.z, (bf16)fa.w };
            *(bf16x4*)&As[row * 40 + c4 * 4] = va;
            float4 fb = *(const float4*)&w_ih[(size_t)(n0 + row) * DIN + k0 + c4 * 4];
            bf16x4 vb = { (bf16)fb.x, (bf16)fb.y, (bf16)fb.z, (bf16)fb.w };
            *(bf16x4*)&Bs[row * 40 + c4 * 4] = vb;
        }
        __syncthreads();
        bf16x8 a0 = *(const bf16x8*)&As[(w * 32 + r) * 40 + q * 8];
        bf16x8 a1 = *(const bf16x8*)&As[(w * 32 + 16 + r) * 40 + q * 8];
        #pragma unroll
        for (int nt = 0; nt < 8; nt++) {
            bf16x8 bb = *(const bf16x8*)&Bs[(nt * 16 + r) * 40 + q * 8];
            acc[0][nt] = __builtin_amdgcn_mfma_f32_16x16x32_bf16(a0, bb, acc[0][nt], 0, 0, 0);
            acc[1][nt] = __builtin_amdgcn_mfma_f32_16x16x32_bf16(a1, bb, acc[1][nt], 0, 0, 0);
        }
    }

    #pragma unroll
    for (int mi = 0; mi < 2; mi++)
        #pragma unroll
        for (int nt = 0; nt < 8; nt++)
            #pragma unroll
            for (int reg = 0; reg < 4; reg++) {
                int gm = m0 + w * 32 + mi * 16 + q * 4 + reg;   // x row = b*T + t
                int n  = n0 + nt * 16 + r;
                int b  = gm >> 10, t = gm & 1023;
                xproj[(((t << 6) + b) << 10) + n] = (bf16)acc[mi][nt][reg];
            }
}

// ---------------------------------------------------------------------------
// Kernel 2: persistent recurrence, NBLK=128 blocks x 512 thr (8 waves).
// Block (fg, half): features fg*16..+16, batches half*32..+32.
// Producer-consumer FLAG lattice (no atomics-RMW, no global barrier):
//   flags[half][bg][fg] = step number whose h-input that producer has stored.
//   Consumer wave (half,bg,kq) polls only ITS 16 source flags (fg in
//   [16kq,16kq+16)) via one dword/lane + __all ballot.
// Producer wave (kq==0) publishes with wave-local vmcnt(0) then a flag store
// -> 3 chained IC hops/step instead of 5.
// h ring buffer depth 8: step t reads slot t&7, writes slot (t+1)&7.
// ---------------------------------------------------------------------------
__global__ __launch_bounds__(512) void rnn_rec(
    const float* __restrict__ w_hh, const float* __restrict__ b_mod,
    const bf16* __restrict__ xproj, u64* __restrict__ hbuf,
    float* __restrict__ hT, u32* __restrict__ flags)
{
    __shared__ bf16 Wl[16 * 1032];       // 33 KB, +8 pad -> 2-way (free)
    __shared__ float Red[2][6 * 288];    // K-partials, parity double-buffer

    const int tid = threadIdx.x;
    const int f0 = (int)(blockIdx.x >> 1) * 16;
    const int fg = (int)(blockIdx.x >> 1);
    const int half = (int)(blockIdx.x & 1);
    const int b0 = half * 32;
    const int w = tid >> 6, lane = tid & 63;
    const int r = lane & 15, q = lane >> 4;
    const int bg = w & 1, kq = w >> 1;
    const int batchA = b0 + bg * 16 + r;       // A-frag row = batch

    // Stage W rows f0..f0+15 (fp32 -> bf16) into LDS, once.
    #pragma unroll
    for (int j = 0; j < 8; j++) {
        int u = tid + j * 512;                  // float4 units, 0..4095
        int row = u >> 8, c4 = u & 255;
        float4 f = *(const float4*)&w_hh[(size_t)(f0 + row) * HID + c4 * 4];
        bf16x4 v = { (bf16)f.x, (bf16)f.y, (bf16)f.z, (bf16)f.w };
        *(bf16x4*)&Wl[row * 1032 + c4 * 4] = v;
    }
    const float bc = b_mod[f0 + r];
    __syncthreads();

    // B-fragments are loop-invariant: hoist into registers (8 x 4 VGPRs).
    const int wkBase = r * 1032 + kq * 256 + q * 8;
    bf16x8 Bf[8];
    #pragma unroll
    for (int ks = 0; ks < 8; ks++)
        Bf[ks] = *(const bf16x8*)&Wl[wkBase + ks * 32];

    u32* hbuf32 = (u32*)hbuf;
    // my poll source: flags[half][bg][16*kq + (lane&15)]
    u32* pollFlag = flags + (((half << 1) + bg) << 6) + kq * 16 + r;
    // my publish target (kq==0 waves only): flags[half][bg][fg]
    u32* pubFlag  = flags + (((half << 1) + bg) << 6) + fg;

    // xproj prefetch for t=0
    float xpv[4];
    if (kq == 0) {
        #pragma unroll
        for (int reg = 0; reg < 4; reg++) {
            int b = b0 + bg * 16 + q * 4 + reg;
            xpv[reg] = (float)xproj[(b << 10) + f0 + r];
        }
    }

    for (int t = 0; t < T_STEPS; t++) {
        const int rp = t & (RING - 1), wp = (t + 1) & (RING - 1);

        // ---- wait for MY 16 producers to have published step t ----
        const u32 tgt = (u32)t;
        for (;;) {
            u32 f = __hip_atomic_load(pollFlag, __ATOMIC_RELAXED, __HIP_MEMORY_SCOPE_AGENT);
            if (__all((int)(f >= tgt))) break;
            __builtin_amdgcn_s_sleep(1);
        }

        // ---- load my K-quarter A fragments (coherent u64 loads) ----
        const u64* H = hbuf + (size_t)rp * 16384 + batchA * 256 + kq * 64 + q * 2;
        union { u64 u[2]; bf16x8 v; } A[8];
        #pragma unroll
        for (int ks = 0; ks < 8; ks++) {
            A[ks].u[0] = __hip_atomic_load(&H[ks*8    ], __ATOMIC_RELAXED, __HIP_MEMORY_SCOPE_AGENT);
            A[ks].u[1] = __hip_atomic_load(&H[ks*8 + 1], __ATOMIC_RELAXED, __HIP_MEMORY_SCOPE_AGENT);
        }

        f32x4 acc0 = {0.f,0.f,0.f,0.f}, acc1 = {0.f,0.f,0.f,0.f};
        #pragma unroll
        for (int ks = 0; ks < 8; ks += 2) {
            acc0 = __builtin_amdgcn_mfma_f32_16x16x32_bf16(A[ks].v,     Bf[ks],     acc0, 0, 0, 0);
            acc1 = __builtin_amdgcn_mfma_f32_16x16x32_bf16(A[ks + 1].v, Bf[ks + 1], acc1, 0, 0, 0);
        }

        // K-partials to LDS (stride 18 -> 2-way, free); parity buffer
        if (kq > 0) {
            const int slot = ((kq - 1) * 2 + bg) * 288;
            #pragma unroll
            for (int reg = 0; reg < 4; reg++)
                Red[t & 1][slot + (q * 4 + reg) * 18 + r] = acc0[reg] + acc1[reg];
        }
        __syncthreads();   // the ONLY block-wide sync per step

        if (kq == 0) {
            float hv4[4];
            #pragma unroll
            for (int reg = 0; reg < 4; reg++) {
                float z = acc0[reg] + acc1[reg];
                #pragma unroll
                for (int p = 0; p < 3; p++)
                    z += Red[t & 1][(p * 2 + bg) * 288 + (q * 4 + reg) * 18 + r];
                z += xpv[reg];
                hv4[reg] = copysignf(fmaxf(fabsf(z) + bc, 0.0f), z);
            }
            if (t == T_STEPS - 1) {
                #pragma unroll
                for (int reg = 0; reg < 4; reg++)
                    hT[(f0 + r) * 64 + b0 + bg * 16 + q * 4 + reg] = hv4[reg];
            } else {
                #pragma unroll
                for (int reg = 0; reg < 4; reg++) {
                    const int b = b0 + bg * 16 + q * 4 + reg;
                    float other = __shfl_xor(hv4[reg], 1);
                    if ((r & 1) == 0) {
                        u32 lo = (u32)__builtin_bit_cast(unsigned short, (bf16)hv4[reg]);
                        u32 hi = (u32)__builtin_bit_cast(unsigned short, (bf16)other);
                        __hip_atomic_store(&hbuf32[(size_t)wp * 32768 + (b << 9) + ((f0 + r) >> 1)],
                                           lo | (hi << 16), __ATOMIC_RELAXED, __HIP_MEMORY_SCOPE_AGENT);
                    }
                }
                // publish: wave-local drain, then flag store (lane 0)
                asm volatile("s_waitcnt vmcnt(0)" ::: "memory");
                if (lane == 0)
                    __hip_atomic_store(pubFlag, (u32)(t + 1), __ATOMIC_RELAXED, __HIP_MEMORY_SCOPE_AGENT);
                // prefetch next step's xproj AFTER the drain+flag (off the chain)
                #pragma unroll
                for (int reg = 0; reg < 4; reg++) {
                    int b = b0 + bg * 16 + q * 4 + reg;
                    xpv[reg] = (float)xproj[((size_t)(t + 1) << 16) + (b << 10) + f0 + r];
                }
            }
        }
    }
}

// ---------------------------------------------------------------------------
// Kernel 3: out[b][c] = hT[:,b] . w_fc[c,:] + b_fc[c]   (fp32)
// ---------------------------------------------------------------------------
__global__ __launch_bounds__(256) void fc_head(
    const float* __restrict__ hT, const float* __restrict__ w_fc,
    const float* __restrict__ b_fc, float* __restrict__ out)
{
    const int tid = threadIdx.x;
    const int b = tid & 63;
    const int c = blockIdx.x * 4 + (tid >> 6);
    float acc = b_fc[c];
    #pragma unroll 8
    for (int k = 0; k < HID; k++)
        acc = fmaf(hT[k * 64 + b], w_fc[(size_t)c * HID + k], acc);
    out[b * 1000 + c] = acc;
}

// ---------------------------------------------------------------------------
extern "C" void kernel_launch(void* const* d_in, const int* in_sizes, int n_in,
                              void* d_out, int out_size, void* d_ws, size_t ws_size,
                              hipStream_t stream)
{
    const float* x     = (const float*)d_in[0];
    const float* w_ih  = (const float*)d_in[1];
    const float* w_hh  = (const float*)d_in[2];
    const float* b_mod = (const float*)d_in[3];
    const float* w_fc  = (const float*)d_in[4];
    const float* b_fc  = (const float*)d_in[5];
    float* out = (float*)d_out;

    char* ws = (char*)d_ws;
    // ws layout:
    //   [0, 128 MiB)              xproj bf16  [T][B][H]
    //   [+0, +1 MiB)              hbuf bf16   ring[8][B][H]
    //   [+1 MiB, +1.25 MiB)       hT fp32     [H][B]
    //   [+1.25 MiB, +1.25M+4K)    flags u32   [half][bg][fg]
    bf16*  xproj = (bf16*)ws;
    u64*   hbuf  = (u64*)(ws + 134217728);
    float* hT    = (float*)(ws + 134217728 + 1048576);
    u32*   flags = (u32*)(ws + 134217728 + 1048576 + 262144);

    // zero h ring slot 0 (t=0 input) and flags (ws is poisoned 0xAA)
    hipMemsetAsync(hbuf, 0, 131072, stream);
    hipMemsetAsync(flags, 0, 4096, stream);

    dim3 g1(512, 8);
    xproj_gemm<<<g1, 256, 0, stream>>>(x, w_ih, xproj);
    rnn_rec<<<NBLK, 512, 0, stream>>>(w_hh, b_mod, xproj, hbuf, hT, flags);
    fc_head<<<250, 256, 0, stream>>>(hT, w_fc, b_fc, out);
}

// Round 6
// 5996.755 us; speedup vs baseline: 1.3453x; 1.3453x over previous
//
#include <hip/hip_runtime.h>

typedef __bf16 bf16;
typedef __bf16 bf16x4 __attribute__((ext_vector_type(4)));
typedef __bf16 bf16x8 __attribute__((ext_vector_type(8)));
typedef float f32x4 __attribute__((ext_vector_type(4)));
typedef unsigned long long u64;
typedef unsigned int u32;

#define T_STEPS 1024
#define BATCH   64
#define DIN     256
#define HID     1024
#define NBLK    128   // 64 feature-groups x 2 batch-halves
#define RING    8     // h ring-buffer depth (slot = t & 7)
#define FSTRIDE 32    // u32s per flag -> one 128-B line per flag

// ---------------------------------------------------------------------------
// Kernel 1: xproj[t][b][h] = sum_d x[b][t][d] * w_ih[h][d]   (bf16 out)
// ---------------------------------------------------------------------------
__global__ __launch_bounds__(256) void xproj_gemm(
    const float* __restrict__ x, const float* __restrict__ w_ih,
    bf16* __restrict__ xproj)
{
    __shared__ bf16 As[128 * 40];
    __shared__ bf16 Bs[128 * 40];
    const int tid = threadIdx.x;
    const int m0 = blockIdx.x * 128;
    const int n0 = blockIdx.y * 128;
    const int w = tid >> 6, lane = tid & 63;
    const int r = lane & 15, q = lane >> 4;

    f32x4 acc[2][8];
    #pragma unroll
    for (int i = 0; i < 2; i++)
        #pragma unroll
        for (int j = 0; j < 8; j++)
            acc[i][j] = (f32x4){0.f, 0.f, 0.f, 0.f};

    for (int kk = 0; kk < 8; kk++) {
        const int k0 = kk * 32;
        __syncthreads();
        #pragma unroll
        for (int j = 0; j < 4; j++) {
            int u = tid + j * 256;
            int row = u >> 3, c4 = u & 7;
            float4 fa = *(const float4*)&x[(size_t)(m0 + row) * DIN + k0 + c4 * 4];
            bf16x4 va = { (bf16)fa.x, (bf16)fa.y, (bf16)fa.z, (bf16)fa.w };
            *(bf16x4*)&As[row * 40 + c4 * 4] = va;
            float4 fb = *(const float4*)&w_ih[(size_t)(n0 + row) * DIN + k0 + c4 * 4];
            bf16x4 vb = { (bf16)fb.x, (bf16)fb.y, (bf16)fb.z, (bf16)fb.w };
            *(bf16x4*)&Bs[row * 40 + c4 * 4] = vb;
        }
        __syncthreads();
        bf16x8 a0 = *(const bf16x8*)&As[(w * 32 + r) * 40 + q * 8];
        bf16x8 a1 = *(const bf16x8*)&As[(w * 32 + 16 + r) * 40 + q * 8];
        #pragma unroll
        for (int nt = 0; nt < 8; nt++) {
            bf16x8 bb = *(const bf16x8*)&Bs[(nt * 16 + r) * 40 + q * 8];
            acc[0][nt] = __builtin_amdgcn_mfma_f32_16x16x32_bf16(a0, bb, acc[0][nt], 0, 0, 0);
            acc[1][nt] = __builtin_amdgcn_mfma_f32_16x16x32_bf16(a1, bb, acc[1][nt], 0, 0, 0);
        }
    }

    #pragma unroll
    for (int mi = 0; mi < 2; mi++)
        #pragma unroll
        for (int nt = 0; nt < 8; nt++)
            #pragma unroll
            for (int reg = 0; reg < 4; reg++) {
                int gm = m0 + w * 32 + mi * 16 + q * 4 + reg;   // x row = b*T + t
                int n  = n0 + nt * 16 + r;
                int b  = gm >> 10, t = gm & 1023;
                xproj[(((t << 6) + b) << 10) + n] = (bf16)acc[mi][nt][reg];
            }
}

// ---------------------------------------------------------------------------
// Kernel 2: persistent recurrence, NBLK=128 blocks x 512 thr (8 waves).
// Block (fg, half): features fg*16..+16, batches half*32..+32.
// Producer-consumer flag lattice; EVERY FLAG ON ITS OWN 128-B LINE:
//   flag(half,bg,fg) at flags[((half*2+bg)*64 + fg) * FSTRIDE].
// Consumer wave (half,bg,kq) polls its 16 producer lines with one 64-lane
// gather (4 lanes per line) + __all; no RMWs, no shared poll lines, no sleep.
// Producer (kq==0) publishes: h stores (sc0sc1) -> vmcnt drain -> flag store.
// h ring buffer depth 8: step t reads slot t&7, writes slot (t+1)&7.
// ---------------------------------------------------------------------------
__global__ __launch_bounds__(512) void rnn_rec(
    const float* __restrict__ w_hh, const float* __restrict__ b_mod,
    const bf16* __restrict__ xproj, u64* __restrict__ hbuf,
    float* __restrict__ hT, u32* __restrict__ flags)
{
    __shared__ bf16 Wl[16 * 1032];       // 33 KB, +8 pad -> 2-way (free)
    __shared__ float Red[2][6 * 288];    // K-partials, parity double-buffer

    const int tid = threadIdx.x;
    const int f0 = (int)(blockIdx.x >> 1) * 16;
    const int fg = (int)(blockIdx.x >> 1);
    const int half = (int)(blockIdx.x & 1);
    const int b0 = half * 32;
    const int w = tid >> 6, lane = tid & 63;
    const int r = lane & 15, q = lane >> 4;
    const int bg = w & 1, kq = w >> 1;
    const int batchA = b0 + bg * 16 + r;       // A-frag row = batch

    // Stage W rows f0..f0+15 (fp32 -> bf16) into LDS, once.
    #pragma unroll
    for (int j = 0; j < 8; j++) {
        int u = tid + j * 512;                  // float4 units, 0..4095
        int row = u >> 8, c4 = u & 255;
        float4 f = *(const float4*)&w_hh[(size_t)(f0 + row) * HID + c4 * 4];
        bf16x4 v = { (bf16)f.x, (bf16)f.y, (bf16)f.z, (bf16)f.w };
        *(bf16x4*)&Wl[row * 1032 + c4 * 4] = v;
    }
    const float bc = b_mod[f0 + r];
    __syncthreads();

    // B-fragments are loop-invariant: hoist into registers (8 x 4 VGPRs).
    const int wkBase = r * 1032 + kq * 256 + q * 8;
    bf16x8 Bf[8];
    #pragma unroll
    for (int ks = 0; ks < 8; ks++)
        Bf[ks] = *(const bf16x8*)&Wl[wkBase + ks * 32];

    u32* hbuf32 = (u32*)hbuf;
    const int dom = (half << 1) + bg;          // flag domain
    // my poll source: flag(half,bg, 16*kq + r) — one line per producer
    u32* pollFlag = flags + (size_t)(dom * 64 + kq * 16 + r) * FSTRIDE;
    // my publish target (kq==0 waves only): flag(half,bg,fg)
    u32* pubFlag  = flags + (size_t)(dom * 64 + fg) * FSTRIDE;

    // xproj prefetch for t=0
    float xpv[4];
    if (kq == 0) {
        #pragma unroll
        for (int reg = 0; reg < 4; reg++) {
            int b = b0 + bg * 16 + q * 4 + reg;
            xpv[reg] = (float)xproj[(b << 10) + f0 + r];
        }
    }

    for (int t = 0; t < T_STEPS; t++) {
        const int rp = t & (RING - 1), wp = (t + 1) & (RING - 1);

        // ---- wait for MY 16 producers (one gather, 16 distinct lines) ----
        const u32 tgt = (u32)t;
        for (;;) {
            u32 f = __hip_atomic_load(pollFlag, __ATOMIC_RELAXED, __HIP_MEMORY_SCOPE_AGENT);
            if (__all((int)(f >= tgt))) break;
        }

        // ---- load my K-quarter A fragments (coherent u64 loads) ----
        const u64* H = hbuf + (size_t)rp * 16384 + batchA * 256 + kq * 64 + q * 2;
        union { u64 u[2]; bf16x8 v; } A[8];
        #pragma unroll
        for (int ks = 0; ks < 8; ks++) {
            A[ks].u[0] = __hip_atomic_load(&H[ks*8    ], __ATOMIC_RELAXED, __HIP_MEMORY_SCOPE_AGENT);
            A[ks].u[1] = __hip_atomic_load(&H[ks*8 + 1], __ATOMIC_RELAXED, __HIP_MEMORY_SCOPE_AGENT);
        }

        f32x4 acc0 = {0.f,0.f,0.f,0.f}, acc1 = {0.f,0.f,0.f,0.f};
        #pragma unroll
        for (int ks = 0; ks < 8; ks += 2) {
            acc0 = __builtin_amdgcn_mfma_f32_16x16x32_bf16(A[ks].v,     Bf[ks],     acc0, 0, 0, 0);
            acc1 = __builtin_amdgcn_mfma_f32_16x16x32_bf16(A[ks + 1].v, Bf[ks + 1], acc1, 0, 0, 0);
        }

        // K-partials to LDS (stride 18 -> 2-way, free); parity buffer
        if (kq > 0) {
            const int slot = ((kq - 1) * 2 + bg) * 288;
            #pragma unroll
            for (int reg = 0; reg < 4; reg++)
                Red[t & 1][slot + (q * 4 + reg) * 18 + r] = acc0[reg] + acc1[reg];
        }
        __syncthreads();   // the ONLY block-wide sync per step

        if (kq == 0) {
            float hv4[4];
            #pragma unroll
            for (int reg = 0; reg < 4; reg++) {
                float z = acc0[reg] + acc1[reg];
                #pragma unroll
                for (int p = 0; p < 3; p++)
                    z += Red[t & 1][(p * 2 + bg) * 288 + (q * 4 + reg) * 18 + r];
                z += xpv[reg];
                hv4[reg] = copysignf(fmaxf(fabsf(z) + bc, 0.0f), z);
            }
            if (t == T_STEPS - 1) {
                #pragma unroll
                for (int reg = 0; reg < 4; reg++)
                    hT[(f0 + r) * 64 + b0 + bg * 16 + q * 4 + reg] = hv4[reg];
            } else {
                #pragma unroll
                for (int reg = 0; reg < 4; reg++) {
                    const int b = b0 + bg * 16 + q * 4 + reg;
                    float other = __shfl_xor(hv4[reg], 1);
                    if ((r & 1) == 0) {
                        u32 lo = (u32)__builtin_bit_cast(unsigned short, (bf16)hv4[reg]);
                        u32 hi = (u32)__builtin_bit_cast(unsigned short, (bf16)other);
                        __hip_atomic_store(&hbuf32[(size_t)wp * 32768 + (b << 9) + ((f0 + r) >> 1)],
                                           lo | (hi << 16), __ATOMIC_RELAXED, __HIP_MEMORY_SCOPE_AGENT);
                    }
                }
                // publish: wave-local drain, then flag store (lane 0)
                asm volatile("s_waitcnt vmcnt(0)" ::: "memory");
                if (lane == 0)
                    __hip_atomic_store(pubFlag, (u32)(t + 1), __ATOMIC_RELAXED, __HIP_MEMORY_SCOPE_AGENT);
                // prefetch next step's xproj AFTER the drain+flag (off the chain)
                #pragma unroll
                for (int reg = 0; reg < 4; reg++) {
                    int b = b0 + bg * 16 + q * 4 + reg;
                    xpv[reg] = (float)xproj[((size_t)(t + 1) << 16) + (b << 10) + f0 + r];
                }
            }
        }
    }
}

// ---------------------------------------------------------------------------
// Kernel 3: out[b][c] = hT[:,b] . w_fc[c,:] + b_fc[c]   (fp32)
// ---------------------------------------------------------------------------
__global__ __launch_bounds__(256) void fc_head(
    const float* __restrict__ hT, const float* __restrict__ w_fc,
    const float* __restrict__ b_fc, float* __restrict__ out)
{
    const int tid = threadIdx.x;
    const int b = tid & 63;
    const int c = blockIdx.x * 4 + (tid >> 6);
    float acc = b_fc[c];
    #pragma unroll 8
    for (int k = 0; k < HID; k++)
        acc = fmaf(hT[k * 64 + b], w_fc[(size_t)c * HID + k], acc);
    out[b * 1000 + c] = acc;
}

// ---------------------------------------------------------------------------
extern "C" void kernel_launch(void* const* d_in, const int* in_sizes, int n_in,
                              void* d_out, int out_size, void* d_ws, size_t ws_size,
                              hipStream_t stream)
{
    const float* x     = (const float*)d_in[0];
    const float* w_ih  = (const float*)d_in[1];
    const float* w_hh  = (const float*)d_in[2];
    const float* b_mod = (const float*)d_in[3];
    const float* w_fc  = (const float*)d_in[4];
    const float* b_fc  = (const float*)d_in[5];
    float* out = (float*)d_out;

    char* ws = (char*)d_ws;
    // ws layout:
    //   [0, 128 MiB)              xproj bf16  [T][B][H]
    //   [+0, +1 MiB)              hbuf bf16   ring[8][B][H]
    //   [+1 MiB, +1.25 MiB)       hT fp32     [H][B]
    //   [+1.25 MiB, +1.25M+32K)   flags u32   [half][bg][fg] x FSTRIDE (1 line each)
    bf16*  xproj = (bf16*)ws;
    u64*   hbuf  = (u64*)(ws + 134217728);
    float* hT    = (float*)(ws + 134217728 + 1048576);
    u32*   flags = (u32*)(ws + 134217728 + 1048576 + 262144);

    // zero h ring slot 0 (t=0 input) and flags (ws is poisoned 0xAA)
    hipMemsetAsync(hbuf, 0, 131072, stream);
    hipMemsetAsync(flags, 0, 256 * FSTRIDE * 4, stream);

    dim3 g1(512, 8);
    xproj_gemm<<<g1, 256, 0, stream>>>(x, w_ih, xproj);
    rnn_rec<<<NBLK, 512, 0, stream>>>(w_hh, b_mod, xproj, hbuf, hT, flags);
    fc_head<<<250, 256, 0, stream>>>(hT, w_fc, b_fc, out);
}